// Round 1
// 567.366 us; speedup vs baseline: 1.0557x; 1.0557x over previous
//
#include <hip/hip_runtime.h>
#include <hip/hip_bf16.h>
#include <math.h>

typedef unsigned short u16;
typedef __attribute__((ext_vector_type(8))) short short8;
typedef __attribute__((ext_vector_type(4))) float floatx4;

#define DEVINL __device__ __forceinline__

DEVINL float bf2f(u16 u) { union { unsigned int i; float f; } v; v.i = ((unsigned int)u) << 16; return v.f; }
DEVINL u16 f2bf(float f) {
  union { unsigned int i; float f; } v; v.f = f;
  unsigned int i = v.i;
  unsigned int r = (i + 0x7fffu + ((i >> 16) & 1u)) >> 16;
  return (u16)r;
}

// ---------------------------------------------------------------------------
// k_prep: all weight conversions in ONE dispatch. grid (768, 5).
//  y=0: cf_w1 f32->bf16 (196608 f4)   y=1: sc_w1 (196608 f4)
//  y=2: cf_w2 (16384 f4)              y=3: sc_w2 pad 64->128 rows (16384 f4)
//  y=4: sc_b2 pad (128 floats)
// ---------------------------------------------------------------------------
__global__ __launch_bounds__(256) void k_prep(
    const float* __restrict__ cf_w1, u16* __restrict__ wc1,
    const float* __restrict__ sc_w1, u16* __restrict__ ws1,
    const float* __restrict__ cf_w2, u16* __restrict__ wc2,
    const float* __restrict__ sc_w2, u16* __restrict__ ws2p,
    const float* __restrict__ sc_b2, float* __restrict__ scb2p) {
  int i = blockIdx.x * 256 + threadIdx.x;
  int job = blockIdx.y;
  if (job == 4) {
    if (i < 128) scb2p[i] = (i < 64) ? sc_b2[i] : 0.f;
    return;
  }
  const float* src = (job == 0) ? cf_w1 : (job == 1) ? sc_w1 : (job == 2) ? cf_w2 : sc_w2;
  u16* dst = (job == 0) ? wc1 : (job == 1) ? ws1 : (job == 2) ? wc2 : ws2p;
  int n4 = (job <= 1) ? 196608 : 16384;
  if (i >= n4) return;
  ushort4 o = {0, 0, 0, 0};
  if (job != 3 || (i >> 7) < 64) {  // job 3: rows >= 64 stay zero
    float4 v = ((const float4*)src)[i];
    o.x = f2bf(v.x); o.y = f2bf(v.y); o.z = f2bf(v.z); o.w = f2bf(v.w);
  }
  ((ushort4*)dst)[i] = o;
}

// ---------------------------------------------------------------------------
// K0: transpose+convert x[b][c][n] (f32) -> xT[b][n][c] (bf16), 64x64 tiles
// ---------------------------------------------------------------------------
__global__ __launch_bounds__(256) void k_transpose(const float* __restrict__ x,
                                                   u16* __restrict__ xT,
                                                   int nC, int nN) {
  __shared__ u16 tile[64 * 65];
  int b = blockIdx.z;
  int c0 = blockIdx.y * 64, n0 = blockIdx.x * 64;
  const float* xb = x + ((long)b * nC + c0) * nN + n0;
  u16* xTb = xT + ((long)b * nN + n0) * nC + c0;
  int tid = threadIdx.x;
#pragma unroll
  for (int p = 0; p < 2; ++p) {
    int u = tid + p * 256;
    int r = u >> 3, nc = (u & 7) * 8;
    const float4* srcp = (const float4*)(xb + (long)r * nN + nc);
    float4 v0 = srcp[0], v1 = srcp[1];
    int base = r * 65 + nc;
    tile[base + 0] = f2bf(v0.x); tile[base + 1] = f2bf(v0.y);
    tile[base + 2] = f2bf(v0.z); tile[base + 3] = f2bf(v0.w);
    tile[base + 4] = f2bf(v1.x); tile[base + 5] = f2bf(v1.y);
    tile[base + 6] = f2bf(v1.z); tile[base + 7] = f2bf(v1.w);
  }
  __syncthreads();
#pragma unroll
  for (int p = 0; p < 2; ++p) {
    int u = tid + p * 256;
    int nr = u >> 3, cc = (u & 7) * 8;
    __align__(16) u16 tmp[8];
#pragma unroll
    for (int j = 0; j < 8; ++j) tmp[j] = tile[(cc + j) * 65 + nr];
    *(uint4*)(xTb + (long)nr * nC + cc) = *(uint4*)(tmp);
  }
}

// ---------------------------------------------------------------------------
// K1: k_gemm256 — 256x256 tile, BK=64, 8-phase schedule with counted vmcnt.
// hT[bz][n][o] = relu(xT[bz][n][:] . W1[o][:] + bias[o]),
//   n in [m0,m0+256), o in [n0,n0+256); o<512 -> (B1,bias1), else (B2,bias2).
// Structure (T2+T3+T4+T5 per the verified 256^2 8-phase template):
//  - 512 threads = 8 waves (2M x 4N); per-wave C = 128x64 (8x4 16x16 frags).
//  - LDS 128 KiB: As/Bs[2 buf][2 halves][128x64], XOR chunk swizzle
//    (chunk ^= row&7, 16B granularity) on BOTH stage-source and ds_read
//    (involution) -> bank-conflict-free (same scheme as before, measured 0).
//  - 4 phases per K-tile; each phase: {4-12 ds_read_b128; 1 half-tile
//    global_load_lds prefetch; s_barrier; lgkmcnt(0); setprio(1); 16 MFMA;
//    setprio(0); [vmcnt(6) at phase 3 only]; s_barrier}.
//  - Prefetch runs 7 half-tile groups ahead; vmcnt(6) = 3 groups in flight.
//    Stage order per tile t: {t+1:Ah1, t+2:Bh0, t+2:Bh1, t+2:Ah0} so every
//    region's last read precedes its overwrite (B fully consumed at phase 0,
//    A half consumed by phase 3).
//  - Tail: boundary before tile 23 uses vmcnt(0); tile 23 stages nothing.
// Accumulation order per element is bitwise identical to the old k_gemm64.
// ---------------------------------------------------------------------------

#define K1_STAGE(S, H, SB)                                                     \
  if ((S) <= 23) {                                                             \
    const u16* gb_ = ((H) < 2) ? Bb : Ab;                                      \
    u16* lb_ = ((H) < 2) ? &Bs[SB][(H) & 1][0] : &As[SB][(H) & 1][0];          \
    int k0_ = (S) << 6;                                                        \
    _Pragma("unroll") for (int l_ = 0; l_ < 2; ++l_) {                         \
      int r_ = (wid * 2 + l_) * 8 + rIn;                                       \
      const u16* src_ =                                                        \
          gb_ + (long)(((H) & 1) * 128 + r_) * 1536 + k0_ + cSw;               \
      __builtin_amdgcn_global_load_lds(                                        \
          (const __attribute__((address_space(1))) void*)src_,                 \
          (__attribute__((address_space(3))) void*)(lb_ + (wid * 2 + l_) * 512), \
          16, 0, 0);                                                           \
    }                                                                          \
  }

#define K1_PHASE(P, SS, SH, SB, VMN)                                           \
  {                                                                            \
    short8 a00 = *(const short8*)(Aw + ((P)*2 + 0) * 1024 + aB0);              \
    short8 a01 = *(const short8*)(Aw + ((P)*2 + 0) * 1024 + aB1);              \
    short8 a10 = *(const short8*)(Aw + ((P)*2 + 1) * 1024 + aB0);              \
    short8 a11 = *(const short8*)(Aw + ((P)*2 + 1) * 1024 + aB1);              \
    if ((P) == 0) {                                                            \
      _Pragma("unroll") for (int n2 = 0; n2 < 4; ++n2) {                       \
        b[n2][0] = *(const short8*)(Bw + n2 * 1024 + aB0);                     \
        b[n2][1] = *(const short8*)(Bw + n2 * 1024 + aB1);                     \
      }                                                                        \
    }                                                                          \
    K1_STAGE(SS, SH, SB)                                                       \
    __builtin_amdgcn_s_barrier();                                              \
    asm volatile("s_waitcnt lgkmcnt(0)" ::: "memory");                         \
    __builtin_amdgcn_s_setprio(1);                                             \
    _Pragma("unroll") for (int n2 = 0; n2 < 4; ++n2) {                         \
      acc[(P)*2][n2] = __builtin_amdgcn_mfma_f32_16x16x32_bf16(                \
          a00, b[n2][0], acc[(P)*2][n2], 0, 0, 0);                             \
      acc[(P)*2][n2] = __builtin_amdgcn_mfma_f32_16x16x32_bf16(                \
          a01, b[n2][1], acc[(P)*2][n2], 0, 0, 0);                             \
      acc[(P)*2 + 1][n2] = __builtin_amdgcn_mfma_f32_16x16x32_bf16(            \
          a10, b[n2][0], acc[(P)*2 + 1][n2], 0, 0, 0);                         \
      acc[(P)*2 + 1][n2] = __builtin_amdgcn_mfma_f32_16x16x32_bf16(            \
          a11, b[n2][1], acc[(P)*2 + 1][n2], 0, 0, 0);                         \
    }                                                                          \
    __builtin_amdgcn_s_setprio(0);                                             \
    if ((VMN) == 6) {                                                          \
      asm volatile("s_waitcnt vmcnt(6)" ::: "memory");                         \
    } else if ((VMN) == 0) {                                                   \
      asm volatile("s_waitcnt vmcnt(0)" ::: "memory");                         \
    }                                                                          \
    __builtin_amdgcn_s_barrier();                                              \
  }

#define K1_TILE(T, BUF, VM)                                                    \
  {                                                                            \
    const u16* Aw = &As[BUF][wm][0];                                           \
    const u16* Bw = &Bs[BUF][wn >> 1][(wn & 1) * 4096];                        \
    short8 b[4][2];                                                            \
    K1_PHASE(0, (T) + 1, 3, (BUF) ^ 1, -1)                                     \
    K1_PHASE(1, (T) + 2, 0, (BUF), -1)                                         \
    K1_PHASE(2, (T) + 2, 1, (BUF), -1)                                         \
    K1_PHASE(3, (T) + 2, 2, (BUF), (VM))                                       \
  }

__global__ __launch_bounds__(512, 2) void k_gemm256(
    const u16* __restrict__ A,                                  // xT [bz][1024][1536]
    const u16* __restrict__ B1, const u16* __restrict__ B2,     // [512][1536] each
    u16* __restrict__ Out,                                      // hT [bz][1024][1024]
    const float* __restrict__ bias1, const float* __restrict__ bias2) {
  __shared__ __align__(16) u16 As[2][2][8192];  // [buf][half][128*64]
  __shared__ __align__(16) u16 Bs[2][2][8192];
  int bz = blockIdx.z;
  int m0 = blockIdx.x * 256, n0 = blockIdx.y * 256;
  const u16* Ab = A + ((long)bz * 1024 + m0) * 1536;
  const u16* Bb = (n0 < 512) ? (B1 + (long)n0 * 1536)
                             : (B2 + (long)(n0 - 512) * 1536);
  int tid = threadIdx.x;
  int lane = tid & 63;
  int wid = tid >> 6;               // 0..7
  int wm = wid >> 2, wn = wid & 3;  // 2M x 4N
  int lane16 = lane & 15, quad = lane >> 4;
  int rIn = lane >> 3;
  int cSw = ((lane & 7) ^ rIn) << 3;  // staging source chunk swizzle (bf16 elems)
  // ds_read offsets: row lane16, chunk (kk*4+quad) ^ (row&7)
  int aB0 = lane16 * 64 + ((quad ^ (lane16 & 7)) << 3);
  int aB1 = lane16 * 64 + (((4 + quad) ^ (lane16 & 7)) << 3);

  floatx4 acc[8][4];
#pragma unroll
  for (int i = 0; i < 8; ++i)
#pragma unroll
    for (int j = 0; j < 4; ++j) acc[i][j] = (floatx4){0.f, 0.f, 0.f, 0.f};

  // prologue: groups 0..6 = tile0 {Bh0,Bh1,Ah0,Ah1} + tile1 {Bh0,Bh1,Ah0}
  K1_STAGE(0, 0, 0)
  K1_STAGE(0, 1, 0)
  K1_STAGE(0, 2, 0)
  K1_STAGE(0, 3, 0)
  K1_STAGE(1, 0, 1)
  K1_STAGE(1, 1, 1)
  K1_STAGE(1, 2, 1)
  asm volatile("s_waitcnt vmcnt(6)" ::: "memory");  // tile0's 4 groups complete
  __builtin_amdgcn_s_barrier();

  for (int it = 0; it < 11; ++it) {
    K1_TILE(2 * it, 0, 6)
    K1_TILE(2 * it + 1, 1, 6)
  }
  K1_TILE(22, 0, 0)   // last boundary must fully drain (tile 23 groups 92..95)
  K1_TILE(23, 1, -1)

  // epilogue: C/D layout col=lane&15, row=quad*4+reg  [m89-verified]
  const float* bcol = (n0 < 512) ? (bias1 + n0) : (bias2 + (n0 - 512));
  long obase = (long)bz * 1048576;
#pragma unroll
  for (int mi = 0; mi < 8; ++mi) {
    int row0 = m0 + wm * 128 + mi * 16 + quad * 4;
#pragma unroll
    for (int ni = 0; ni < 4; ++ni) {
      int colw = wn * 64 + ni * 16 + lane16;
      float bb = bcol[colw];
#pragma unroll
      for (int r = 0; r < 4; ++r) {
        float v = fmaxf(acc[mi][ni][r] + bb, 0.f);
        Out[obase + (long)(row0 + r) * 1024 + n0 + colw] = f2bf(v);
      }
    }
  }
}

// ---------------------------------------------------------------------------
// K2 fused: grid (8, 2, c). y=0: f = wc2 . hT_cf^T + cf_b2
//                           y=1: scr = ws2p . hT_sc^T + scb2p
// M=128, N=1024, K=512. BK=64 XOR-swizzled structure.
// ---------------------------------------------------------------------------
__global__ __launch_bounds__(256) void k_k2dual(
    const u16* __restrict__ wA, const u16* __restrict__ wB,
    const u16* __restrict__ hT, u16* __restrict__ fOut, u16* __restrict__ sOut,
    const float* __restrict__ bA, const float* __restrict__ bB) {
  __shared__ __align__(16) u16 As[128 * 64];
  __shared__ __align__(16) u16 Bs[128 * 64];
  int sel = blockIdx.y, bz = blockIdx.z;
  const u16* A = sel ? wB : wA;                               // [128][512]
  const u16* Bbase = hT + (long)bz * 1048576 + (sel ? 512 : 0);
  u16* Out = (sel ? sOut : fOut) + (long)bz * 131072;
  const float* bias = sel ? bB : bA;
  int n0 = blockIdx.x * 128;
  int tid = threadIdx.x;
  int lane = tid & 63;
  int lane16 = lane & 15, quad = lane >> 4;
  int wid = tid >> 6;
  int wm = wid >> 1, wn = wid & 1;
  int rIn = lane >> 3;
  int kkSw = ((lane & 7) ^ rIn) * 8;

  floatx4 acc[4][4];
#pragma unroll
  for (int i = 0; i < 4; ++i)
#pragma unroll
    for (int j = 0; j < 4; ++j) acc[i][j] = (floatx4){0.f, 0.f, 0.f, 0.f};

  for (int k0 = 0; k0 < 512; k0 += 64) {
    __syncthreads();
#pragma unroll
    for (int h = 0; h < 4; ++h) {
      int ch = wid * 4 + h;
      int r = ch * 8 + rIn;
      const u16* srcA = A + (long)r * 512 + k0 + kkSw;
      __builtin_amdgcn_global_load_lds(
          (const __attribute__((address_space(1))) void*)srcA,
          (__attribute__((address_space(3))) void*)&As[ch * 512], 16, 0, 0);
      const u16* srcB = Bbase + (long)(n0 + r) * 1024 + k0 + kkSw;
      __builtin_amdgcn_global_load_lds(
          (const __attribute__((address_space(1))) void*)srcB,
          (__attribute__((address_space(3))) void*)&Bs[ch * 512], 16, 0, 0);
    }
    __syncthreads();
#pragma unroll
    for (int h2 = 0; h2 < 2; ++h2) {
      short8 af[4], bfr[4];
#pragma unroll
      for (int t = 0; t < 4; ++t) {
        int ra = wm * 64 + t * 16 + lane16;
        af[t] = *(const short8*)&As[ra * 64 + (((h2 * 4 + quad) ^ (ra & 7)) * 8)];
      }
#pragma unroll
      for (int t = 0; t < 4; ++t) {
        int rb = wn * 64 + t * 16 + lane16;
        bfr[t] = *(const short8*)&Bs[rb * 64 + (((h2 * 4 + quad) ^ (rb & 7)) * 8)];
      }
#pragma unroll
      for (int i = 0; i < 4; ++i)
#pragma unroll
        for (int j = 0; j < 4; ++j)
          acc[i][j] = __builtin_amdgcn_mfma_f32_16x16x32_bf16(af[i], bfr[j],
                                                              acc[i][j], 0, 0, 0);
    }
  }
#pragma unroll
  for (int i = 0; i < 4; ++i) {
    int rowb = wm * 64 + i * 16 + quad * 4;
#pragma unroll
    for (int j = 0; j < 4; ++j) {
      int col = n0 + wn * 64 + j * 16 + lane16;
#pragma unroll
      for (int r = 0; r < 4; ++r) {
        int row = rowb + r;
        Out[(long)row * 1024 + col] = f2bf(acc[i][j][r] + bias[row]);
      }
    }
  }
}

// ---------------------------------------------------------------------------
// K3: log-space Sinkhorn, one block per batch. scores bf16, 128-row stride
// (rows 0..63 valid).
// ---------------------------------------------------------------------------
__global__ __launch_bounds__(1024) void k_sinkhorn(
    const u16* __restrict__ S, const float* __restrict__ alphaPtr,
    float lmu, float lmu_bin, float lnu, float norm, u16* __restrict__ P) {
  __shared__ float u_[65];
  __shared__ float v_[1024];
  int b = blockIdx.x, tid = threadIdx.x;
  const u16* Sb = S + (long)b * 131072;
  float alpha = *alphaPtr;
  v_[tid] = 0.f;
  __syncthreads();
  int wid = tid >> 6, lane = tid & 63;
  for (int it = 0; it < 3; ++it) {
    for (int i = wid; i < 65; i += 16) {   // u-pass: wave per row
      float vals[16];
      float mx = -3.4e38f;
#pragma unroll
      for (int s = 0; s < 16; ++s) {
        int j = lane + s * 64;
        float z = (i < 64 ? bf2f(Sb[i * 1024 + j]) : alpha) + v_[j];
        vals[s] = z;
        mx = fmaxf(mx, z);
      }
#pragma unroll
      for (int off = 32; off > 0; off >>= 1) mx = fmaxf(mx, __shfl_xor(mx, off));
      float sum = 0.f;
#pragma unroll
      for (int s = 0; s < 16; ++s) sum += __expf(vals[s] - mx);
#pragma unroll
      for (int off = 32; off > 0; off >>= 1) sum += __shfl_xor(sum, off);
      if (lane == 0) u_[i] = (i < 64 ? lmu : lmu_bin) - (mx + __logf(sum));
    }
    __syncthreads();
    {  // v-pass: thread per column, two-pass LSE over m=65
      float mx = alpha + u_[64];
#pragma unroll 8
      for (int i = 0; i < 64; ++i)
        mx = fmaxf(mx, bf2f(Sb[i * 1024 + tid]) + u_[i]);
      float sum = __expf(alpha + u_[64] - mx);
#pragma unroll 8
      for (int i = 0; i < 64; ++i)
        sum += __expf(bf2f(Sb[i * 1024 + tid]) + u_[i] - mx);
      v_[tid] = lnu - (mx + __logf(sum));
    }
    __syncthreads();
  }
  float vj = v_[tid];
  u16* Pb = P + (long)b * 65536;
#pragma unroll 8
  for (int i = 0; i < 64; ++i) {
    float z = bf2f(Sb[i * 1024 + tid]) + u_[i] + vj - norm;
    Pb[i * 1024 + tid] = f2bf(__expf(fminf(z, 1.0f)));  // z<=0 mathematically
  }
}

// ---------------------------------------------------------------------------
// K4: split-K agg partials. aggP[kc][b][128][64] = f[b,128,ks] P[b,64,ks]^T
// ---------------------------------------------------------------------------
__global__ __launch_bounds__(256) void k_agg(const u16* __restrict__ f,
                                             const u16* __restrict__ P,
                                             float* __restrict__ aggP) {
  __shared__ __align__(16) u16 Fs[128 * 32];
  __shared__ __align__(16) u16 Ps[64 * 32];
  int bz = blockIdx.z, kc = blockIdx.x;
  const u16* Fb = f + (long)bz * 128 * 1024;
  const u16* Pb = P + (long)bz * 64 * 1024;
  int tid = threadIdx.x, wid = tid >> 6, lane = tid & 63;
  int lane16 = lane & 15, quad = lane >> 4;
  int rA0 = lane >> 2, kk = (lane & 3) * 8;

  floatx4 acc[2][4];
#pragma unroll
  for (int i = 0; i < 2; ++i)
#pragma unroll
    for (int j = 0; j < 4; ++j) acc[i][j] = (floatx4){0.f, 0.f, 0.f, 0.f};

  for (int k0 = kc * 256; k0 < kc * 256 + 256; k0 += 32) {
    __syncthreads();
#pragma unroll
    for (int h = 0; h < 2; ++h) {
      int ch = wid * 2 + h;
      int r = ch * 16 + rA0;
      const u16* srcF = Fb + (long)r * 1024 + k0 + kk;
      __builtin_amdgcn_global_load_lds(
          (const __attribute__((address_space(1))) void*)srcF,
          (__attribute__((address_space(3))) void*)&Fs[ch * 512], 16, 0, 0);
    }
    {
      int r = wid * 16 + rA0;
      const u16* srcP = Pb + (long)r * 1024 + k0 + kk;
      __builtin_amdgcn_global_load_lds(
          (const __attribute__((address_space(1))) void*)srcP,
          (__attribute__((address_space(3))) void*)&Ps[wid * 512], 16, 0, 0);
    }
    __syncthreads();
    short8 af[2], bfr[4];
#pragma unroll
    for (int t = 0; t < 2; ++t)
      af[t] = *(const short8*)&Fs[(wid * 32 + t * 16 + lane16) * 32 + quad * 8];
#pragma unroll
    for (int j = 0; j < 4; ++j)
      bfr[j] = *(const short8*)&Ps[(j * 16 + lane16) * 32 + quad * 8];
#pragma unroll
    for (int i = 0; i < 2; ++i)
#pragma unroll
      for (int j = 0; j < 4; ++j)
        acc[i][j] = __builtin_amdgcn_mfma_f32_16x16x32_bf16(af[i], bfr[j],
                                                            acc[i][j], 0, 0, 0);
  }
  float* ab = aggP + ((long)kc * 32 + bz) * 8192;
#pragma unroll
  for (int i = 0; i < 2; ++i)
#pragma unroll
    for (int j = 0; j < 4; ++j)
#pragma unroll
      for (int r = 0; r < 4; ++r) {
        int row = wid * 32 + i * 16 + quad * 4 + r;
        int col = j * 16 + lane16;
        ab[row * 64 + col] = acc[i][j][r];
      }
}

// ---------------------------------------------------------------------------
// token MLP, parallelized.
// ---------------------------------------------------------------------------
DEVINL float waveSum(float x) {
#pragma unroll
  for (int off = 32; off > 0; off >>= 1) x += __shfl_xor(x, off);
  return x;
}

__global__ __launch_bounds__(256) void k_mlp1(const float* __restrict__ t,
                                              const float* __restrict__ w1,
                                              const float* __restrict__ b1,
                                              float* __restrict__ h1) {
  __shared__ float tl[1536];
  int b = blockIdx.y, og = blockIdx.x;
  int tid = threadIdx.x, wid = tid >> 6, lane = tid & 63;
  for (int i = tid; i < 1536; i += 256) tl[i] = t[b * 1536 + i];
  __syncthreads();
#pragma unroll 4
  for (int oi = 0; oi < 16; ++oi) {
    int o = og * 64 + wid * 16 + oi;
    const float* wr = w1 + (long)o * 1536;
    float acc = 0.f;
#pragma unroll
    for (int s = 0; s < 24; ++s) { int c = lane + s * 64; acc += tl[c] * wr[c]; }
    acc = waveSum(acc);
    if (lane == 0) h1[b * 512 + o] = fmaxf(acc + b1[o], 0.f);
  }
}

__global__ __launch_bounds__(256) void k_mlp2(const float* __restrict__ h1,
                                              const float* __restrict__ w2,
                                              const float* __restrict__ b2,
                                              float* __restrict__ tk) {
  __shared__ float hl[512];
  int b = blockIdx.y, og = blockIdx.x;
  int tid = threadIdx.x, wid = tid >> 6, lane = tid & 63;
  for (int i = tid; i < 512; i += 256) hl[i] = h1[b * 512 + i];
  __syncthreads();
#pragma unroll 4
  for (int oi = 0; oi < 16; ++oi) {
    int o = og * 64 + wid * 16 + oi;
    const float* wr = w2 + (long)o * 512;
    float acc = 0.f;
#pragma unroll
    for (int s = 0; s < 8; ++s) { int c = lane + s * 64; acc += hl[c] * wr[c]; }
    acc = waveSum(acc);
    if (lane == 0) tk[b * 256 + o] = acc + b2[o];
  }
}

// ---------------------------------------------------------------------------
// K5: norms + output.
// ---------------------------------------------------------------------------
DEVINL float blockSum256(float x, float* red) {
#pragma unroll
  for (int off = 32; off > 0; off >>= 1) x += __shfl_xor(x, off);
  int wid = threadIdx.x >> 6;
  __syncthreads();
  if ((threadIdx.x & 63) == 0) red[wid] = x;
  __syncthreads();
  return red[0] + red[1] + red[2] + red[3];
}

__global__ __launch_bounds__(256) void k_norms(const float* __restrict__ tk,
                                               const float* __restrict__ aggP,
                                               float* __restrict__ out) {
  __shared__ float asum[8192];
  __shared__ float cn[64];
  __shared__ float red[4];
  int b = blockIdx.x, tid = threadIdx.x;
  const float* a0 = aggP + (long)b * 8192;
  for (int idx = tid; idx < 8192; idx += 256)
    asum[idx] = a0[idx] + a0[32 * 8192 + idx] + a0[64 * 8192 + idx] +
                a0[96 * 8192 + idx];
  __syncthreads();
  float tkv = tk[b * 256 + tid];
  float tss = blockSum256(tkv * tkv, red);
  float tn = fmaxf(sqrtf(tss), 1e-12f);
  if (tid < 64) {
    float s = 0.f;
    for (int l = 0; l < 128; ++l) { float a = asum[l * 64 + tid]; s += a * a; }
    cn[tid] = fmaxf(sqrtf(s), 1e-12f);
  }
  __syncthreads();
  float gs = (tkv / tn) * (tkv / tn);
  for (int idx = tid; idx < 8192; idx += 256) {
    float a = asum[idx] / cn[idx & 63];
    gs += a * a;
  }
  float G = blockSum256(gs, red);
  float inv = 1.f / fmaxf(sqrtf(G), 1e-12f);
  float* ob = out + (long)b * 8448;
  ob[tid] = tkv / tn * inv;
  for (int idx = tid; idx < 8192; idx += 256)
    ob[256 + idx] = asum[idx] / cn[idx & 63] * inv;
}

// ---------------------------------------------------------------------------
extern "C" void kernel_launch(void* const* d_in, const int* in_sizes, int n_in,
                              void* d_out, int out_size, void* d_ws,
                              size_t ws_size, hipStream_t stream) {
  const float* x = (const float*)d_in[0];
  const float* t = (const float*)d_in[1];
  const float* cf_w1 = (const float*)d_in[2];
  const float* cf_b1 = (const float*)d_in[3];
  const float* cf_w2 = (const float*)d_in[4];
  const float* cf_b2 = (const float*)d_in[5];
  const float* sc_w1 = (const float*)d_in[6];
  const float* sc_b1 = (const float*)d_in[7];
  const float* sc_w2 = (const float*)d_in[8];
  const float* sc_b2 = (const float*)d_in[9];
  const float* tk_w1 = (const float*)d_in[10];
  const float* tk_b1 = (const float*)d_in[11];
  const float* tk_w2 = (const float*)d_in[12];
  const float* tk_b2 = (const float*)d_in[13];
  const float* dust = (const float*)d_in[14];
  float* out = (float*)d_out;

  // workspace layout (all 16B-multiples)
  char* ws = (char*)d_ws;
  size_t off = 0;
  u16* wc1 = (u16*)(ws + off); off += (size_t)512 * 1536 * 2;        // cf_w1 bf16
  u16* ws1 = (u16*)(ws + off); off += (size_t)512 * 1536 * 2;        // sc_w1 bf16
  u16* wc2 = (u16*)(ws + off); off += (size_t)128 * 512 * 2;         // cf_w2 bf16
  u16* ws2p = (u16*)(ws + off); off += (size_t)128 * 512 * 2;        // sc_w2 padded
  float* scb2p = (float*)(ws + off); off += (size_t)128 * 4;         // sc_b2 padded
  u16* f = (u16*)(ws + off);   off += (size_t)32 * 128 * 1024 * 2;   // 8 MB
  u16* scr = (u16*)(ws + off); off += (size_t)32 * 128 * 1024 * 2;   // 8 MB
  u16* P = (u16*)(ws + off);   off += (size_t)32 * 64 * 1024 * 2;    // 4 MB
  float* aggP = (float*)(ws + off); off += (size_t)4 * 32 * 128 * 64 * 4; // 4 MB
  float* h1ws = (float*)(ws + off); off += (size_t)32 * 512 * 4;     // 64 KB
  float* tkws = (float*)(ws + off); off += (size_t)32 * 256 * 4;     // 32 KB
  size_t fixed = off;
  size_t perB = (size_t)1024 * 1536 * 2 + (size_t)1024 * 1024 * 2;   // xT+hT
  int c = 1;
  const int cands[6] = {32, 16, 8, 4, 2, 1};
  for (int k = 0; k < 6; ++k)
    if (fixed + (size_t)cands[k] * perB <= ws_size) { c = cands[k]; break; }
  u16* xT = (u16*)(ws + fixed);
  u16* hT = (u16*)(ws + fixed + (size_t)c * 1024 * 1536 * 2);

  // weight prep (one dispatch)
  k_prep<<<dim3(768, 5), 256, 0, stream>>>(cf_w1, wc1, sc_w1, ws1, cf_w2, wc2,
                                           sc_w2, ws2p, sc_b2, scb2p);

  // token MLP (independent of the conv path — launch early)
  k_mlp1<<<dim3(8, 32), 256, 0, stream>>>(t, tk_w1, tk_b1, h1ws);
  k_mlp2<<<dim3(4, 32), 256, 0, stream>>>(h1ws, tk_w2, tk_b2, tkws);

  float norm = -logf(1088.f);          // -log(m+n), m=64 n=1024
  float lmu = norm;
  float lmu_bin = logf(960.f) + norm;  // log(n-m) + norm
  float lnu = norm;

  for (int cb = 0; cb < 32; cb += c) {
    // K0: x[b][c][n] f32 -> xT[b][n][c] bf16
    k_transpose<<<dim3(16, 24, c), 256, 0, stream>>>(
        x + (size_t)cb * 1536 * 1024, xT, 1536, 1024);
    // K1: hT[b][n][o] = relu(xT . W1^T + b1), fused cf(o<512) + sc(o>=512)
    //     256^2-tile 8-phase counted-vmcnt schedule
    k_gemm256<<<dim3(4, 4, c), 512, 0, stream>>>(xT, wc1, ws1, hT, cf_b1,
                                                 sc_b1);
    // K2 fused: f + scores in one dispatch
    k_k2dual<<<dim3(8, 2, c), 256, 0, stream>>>(
        wc2, ws2p, hT, f + (size_t)cb * 131072, scr + (size_t)cb * 131072,
        cf_b2, scb2p);
  }
  // K3: Sinkhorn -> P bf16 [b][64][1024]
  k_sinkhorn<<<32, 1024, 0, stream>>>(scr, dust, lmu, lmu_bin, lnu, norm, P);
  // K4: split-K agg partials [4][32][128][64]
  k_agg<<<dim3(4, 1, 32), 256, 0, stream>>>(f, P, aggP);
  // K5: norms + output
  k_norms<<<32, 256, 0, stream>>>(tkws, aggP, out);
}